// Round 6
// baseline (420.131 us; speedup 1.0000x reference)
//
#include <hip/hip_runtime.h>
#include <math.h>

typedef unsigned short u16;
typedef unsigned int u32;
typedef unsigned long long u64;
typedef __attribute__((ext_vector_type(8))) short bf16x8;
typedef __attribute__((ext_vector_type(4))) float f32x4;

#define L      1024
#define NH     8
#define DH     64
#define DR     32
#define KTS    96
#define LWIN   64
#define NKV    1024   // [kc 512 | vc 512]
#define NQP    768    // [qc 512 | qrp 256]
#define CCW    352    // compact fp32: [qi 256|ki 64|kr 32]

__device__ __forceinline__ u16 bf16_rn(float x) {
  unsigned u = __float_as_uint(x);
  return (u16)((u + 0x7fffu + ((u >> 16) & 1u)) >> 16);
}
__device__ __forceinline__ float bf16_tof(u16 h) {
  return __uint_as_float(((unsigned)h) << 16);
}
__device__ __forceinline__ float softplusf(float x) {
  return fmaxf(x, 0.f) + log1pf(expf(-fabsf(x)));
}
__device__ __forceinline__ f32x4 mfma16(bf16x8 a, bf16x8 b, f32x4 c) {
  return __builtin_amdgcn_mfma_f32_16x16x32_bf16(a, b, c, 0, 0, 0);
}
__device__ __forceinline__ u64 pack4(u16 a, u16 b, u16 c, u16 d) {
  return (u64)a | ((u64)b << 16) | ((u64)c << 32) | ((u64)d << 48);
}
__device__ __forceinline__ u64 umax64(u64 a, u64 b) { return a > b ? a : b; }

// ---------------- weight transpose + bf16 split ([K][N] -> [N][K] planes) ----
struct TSrc { const float* p; int n0, w; };

__global__ __launch_bounds__(256) void wsplit(
    TSrc s0, TSrc s1, TSrc s2, TSrc s3, TSrc s4,
    int K, u16* __restrict__ Ph, u16* __restrict__ Pm, u16* __restrict__ Pl) {
  __shared__ float tile[32][33];
  const int k0 = blockIdx.y * 32, n0 = blockIdx.x * 32;
  const int tid = threadIdx.x;
  const float* sp = nullptr; int off = 0, w = 0;
  if (s0.p && n0 >= s0.n0 && n0 < s0.n0 + s0.w) { sp = s0.p; off = s0.n0; w = s0.w; }
  else if (s1.p && n0 >= s1.n0 && n0 < s1.n0 + s1.w) { sp = s1.p; off = s1.n0; w = s1.w; }
  else if (s2.p && n0 >= s2.n0 && n0 < s2.n0 + s2.w) { sp = s2.p; off = s2.n0; w = s2.w; }
  else if (s3.p && n0 >= s3.n0 && n0 < s3.n0 + s3.w) { sp = s3.p; off = s3.n0; w = s3.w; }
  else if (s4.p && n0 >= s4.n0 && n0 < s4.n0 + s4.w) { sp = s4.p; off = s4.n0; w = s4.w; }
  {
    const int kl = tid >> 3, n4 = (tid & 7) * 4;
    float4 v = make_float4(0.f, 0.f, 0.f, 0.f);
    if (sp) v = *(const float4*)(sp + (size_t)(k0 + kl) * w + (n0 - off) + n4);
    tile[kl][n4 + 0] = v.x; tile[kl][n4 + 1] = v.y;
    tile[kl][n4 + 2] = v.z; tile[kl][n4 + 3] = v.w;
  }
  __syncthreads();
  const int nl = tid >> 3, k4 = (tid & 7) * 4;
  u16 h[4], m[4], lo[4];
#pragma unroll
  for (int j = 0; j < 4; ++j) {
    float x = tile[k4 + j][nl];
    u16 hh = bf16_rn(x); float r = x - bf16_tof(hh);
    h[j] = hh;
    if (Pm) { u16 mm = bf16_rn(r); r = r - bf16_tof(mm); m[j] = mm; }
    lo[j] = bf16_rn(r);
  }
  const size_t o = (size_t)(n0 + nl) * K + k0 + k4;
  *(u64*)(Ph + o) = pack4(h[0], h[1], h[2], h[3]);
  if (Pm) *(u64*)(Pm + o) = pack4(m[0], m[1], m[2], m[3]);
  *(u64*)(Pl + o) = pack4(lo[0], lo[1], lo[2], lo[3]);
}

// ---------------- x -> h/m/l planes (row-major, elementwise) -----------------
__global__ __launch_bounds__(256) void xsplit(
    const float* __restrict__ x, u16* __restrict__ Xh, u16* __restrict__ Xm,
    u16* __restrict__ Xl) {
  const int i = (blockIdx.x * 256 + threadIdx.x) * 4;
  float4 v = *(const float4*)(x + i);
  float e[4] = {v.x, v.y, v.z, v.w};
  u16 h[4], m[4], lo[4];
#pragma unroll
  for (int j = 0; j < 4; ++j) {
    u16 hh = bf16_rn(e[j]); float r = e[j] - bf16_tof(hh);
    h[j] = hh;
    u16 mm = bf16_rn(r); r = r - bf16_tof(mm); m[j] = mm;
    lo[j] = bf16_rn(r);
  }
  *(u64*)(Xh + i) = pack4(h[0], h[1], h[2], h[3]);
  *(u64*)(Xm + i) = pack4(m[0], m[1], m[2], m[3]);
  *(u64*)(Xl + i) = pack4(lo[0], lo[1], lo[2], lo[3]);
}

// ---------------- bf16-split MFMA GEMM (all-plane staging) -------------------
// C = A @ B; A as NS row-major [M][K] bf16 planes, B as NS [N][K] planes.
// 128x128 tile, BK=32, 4 waves 2x2, LDS stride 40 u16 (conflict-free b128).
// OUT: 0 = fp32 C; 1 = h/l u16 planes Ch/Cl; 2 = fp32 compact (col<CCW).
struct GArg {
  const u16 *A0, *A1, *A2;
  const u16 *B0, *B1, *B2;
  float* C; u16 *Ch, *Cl;
  int lda, ldc, K, nbn;
};

template <int NS, int OUT>
__global__ __launch_bounds__(256) void mfma_gemm(GArg g0, GArg g1) {
  GArg g = (blockIdx.z == 0) ? g0 : g1;
  if ((int)blockIdx.x >= g.nbn) return;
  __shared__ u16 Al[NS * 5120];
  __shared__ u16 Bl[NS * 5120];
  const int tid = threadIdx.x;
  const int l = tid & 63, w = tid >> 6;
  const int wr = w >> 1, wc = w & 1;
  const int l15 = l & 15, l4 = l >> 4;
  const int bm = blockIdx.y * 128, bn = blockIdx.x * 128;
  const int ar2 = tid >> 1, akc = (tid & 1) * 16;  // A: row ar2, u16 cols akc..+15
  const int brr = tid >> 2, bkc = (tid & 3) * 8;   // B: rows brr,brr+64, cols bkc..+7

  f32x4 acc[4][4];
#pragma unroll
  for (int i = 0; i < 4; ++i)
#pragma unroll
    for (int j = 0; j < 4; ++j) acc[i][j] = (f32x4){0.f, 0.f, 0.f, 0.f};

  for (int k0 = 0; k0 < g.K; k0 += 32) {
#pragma unroll
    for (int p = 0; p < NS; ++p) {
      const u16* Ap = (p == 0) ? g.A0 : (p == 1 ? g.A1 : g.A2);
      const size_t ab = (size_t)(bm + ar2) * g.lda + k0 + akc;
      *(uint4*)&Al[p * 5120 + ar2 * 40 + akc] = *(const uint4*)(Ap + ab);
      *(uint4*)&Al[p * 5120 + ar2 * 40 + akc + 8] = *(const uint4*)(Ap + ab + 8);
      const u16* Bp = (p == 0) ? g.B0 : (p == 1 ? g.B1 : g.B2);
#pragma unroll
      for (int i = 0; i < 2; ++i) {
        const int row = brr + i * 64;
        *(uint4*)&Bl[p * 5120 + row * 40 + bkc] =
            *(const uint4*)(Bp + (size_t)(bn + row) * g.K + k0 + bkc);
      }
    }
    __syncthreads();
    bf16x8 af[NS][4], bf[NS][4];
#pragma unroll
    for (int f = 0; f < 4; ++f) {
      const int arow = wr * 64 + f * 16 + l15;
      const int brow = wc * 64 + f * 16 + l15;
#pragma unroll
      for (int p = 0; p < NS; ++p) {
        af[p][f] = *(const bf16x8*)&Al[p * 5120 + arow * 40 + l4 * 8];
        bf[p][f] = *(const bf16x8*)&Bl[p * 5120 + brow * 40 + l4 * 8];
      }
    }
#pragma unroll
    for (int fm = 0; fm < 4; ++fm)
#pragma unroll
      for (int fn = 0; fn < 4; ++fn) {
        f32x4 c = acc[fm][fn];
        c = mfma16(af[0][fm], bf[0][fn], c);
        c = mfma16(af[0][fm], bf[1][fn], c);
        c = mfma16(af[1][fm], bf[0][fn], c);
        if (NS == 3) {
          c = mfma16(af[0][fm], bf[2][fn], c);
          c = mfma16(af[2][fm], bf[0][fn], c);
          c = mfma16(af[1][fm], bf[1][fn], c);
        }
        acc[fm][fn] = c;
      }
    __syncthreads();
  }
#pragma unroll
  for (int fm = 0; fm < 4; ++fm)
#pragma unroll
    for (int j = 0; j < 4; ++j) {
      const int row = bm + wr * 64 + fm * 16 + l4 * 4 + j;
#pragma unroll
      for (int fn = 0; fn < 4; ++fn) {
        const int col = bn + wc * 64 + fn * 16 + l15;
        const float val = acc[fm][fn][j];
        if (OUT == 0) {
          g.C[(size_t)row * g.ldc + col] = val;
        } else if (OUT == 1) {
          u16 hh = bf16_rn(val);
          g.Ch[(size_t)row * g.ldc + col] = hh;
          g.Cl[(size_t)row * g.ldc + col] = bf16_rn(val - bf16_tof(hh));
        } else {
          if (col < CCW) g.C[(size_t)row * CCW + col] = val;
        }
      }
    }
}

// ------------- LightningIndexer scores + TokenSelector top-k -----------------
#define KPL 15  // ceil(960/64)

__global__ __launch_bounds__(256) void indexer_topk(
    const float* __restrict__ qiki, const float* __restrict__ idx_w,
    int* __restrict__ idx_sel) {
  const int wave = threadIdx.x >> 6;
  const int lane = threadIdx.x & 63;
  const int bt = blockIdx.x * 4 + wave;
  const int b = bt >> 10;
  const int t = bt & 1023;
  int* out = idx_sel + (size_t)bt * KTS;

  __shared__ __align__(16) float qsh[4][256];
  *(float4*)&qsh[wave][lane * 4] =
      *(const float4*)(qiki + (size_t)bt * CCW + lane * 4);
  const float w0 = idx_w[0], w1 = idx_w[1], w2 = idx_w[2], w3 = idx_w[3];
  __syncthreads();

  if (t < LWIN) {
    out[lane] = lane;
    if (lane < 32) out[64 + lane] = 64 + lane;
    return;
  }
  out[lane] = t - 63 + lane;
  const int nf = t - 63;

  const float* kib = qiki + (size_t)b * L * CCW + 256;
  const float* qw = qsh[wave];
  u64 key[KPL];
#pragma unroll
  for (int j = 0; j < KPL; ++j) {
    u64 k = 0ull;
    const int s = j * 64 + lane;
    if (s < nf) {
      const float* kr = kib + (size_t)s * CCW;
      float a0 = 0.f, a1 = 0.f, a2 = 0.f, a3 = 0.f;
#pragma unroll 4
      for (int d = 0; d < 64; d += 4) {
        float4 kv = *(const float4*)(kr + d);
        float4 q0 = *(const float4*)&qw[d];
        float4 q1 = *(const float4*)&qw[64 + d];
        float4 q2 = *(const float4*)&qw[128 + d];
        float4 q3 = *(const float4*)&qw[192 + d];
        a0 += q0.x * kv.x + q0.y * kv.y + q0.z * kv.z + q0.w * kv.w;
        a1 += q1.x * kv.x + q1.y * kv.y + q1.z * kv.z + q1.w * kv.w;
        a2 += q2.x * kv.x + q2.y * kv.y + q2.z * kv.z + q2.w * kv.w;
        a3 += q3.x * kv.x + q3.y * kv.y + q3.z * kv.z + q3.w * kv.w;
      }
      float I = w0 * fmaxf(a0, 0.f) + w1 * fmaxf(a1, 0.f)
              + w2 * fmaxf(a2, 0.f) + w3 * fmaxf(a3, 0.f);
      unsigned ib = __float_as_uint(I);
      if (ib == 0x80000000u) ib = 0u;
      ib = (ib & 0x80000000u) ? ~ib : (ib | 0x80000000u);
      k = ((u64)ib << 32) | (u64)(0xFFFFFFFFu - (unsigned)s);
    }
    key[j] = k;
  }

  u64 lm = key[0];
#pragma unroll
  for (int j = 1; j < KPL; ++j) lm = umax64(lm, key[j]);

  const int topM = nf < 32 ? nf : 32;
  for (int it = 0; it < topM; ++it) {
    u64 m = lm;
#pragma unroll
    for (int off = 32; off > 0; off >>= 1) m = umax64(m, __shfl_xor(m, off));
    if (lane == 0)
      out[64 + it] = (int)(0xFFFFFFFFu - (unsigned)(m & 0xFFFFFFFFull));
    if (lm == m) {
#pragma unroll
      for (int j = 0; j < KPL; ++j)
        if (key[j] == m) key[j] = 0ull;
      lm = key[0];
#pragma unroll
      for (int j = 1; j < KPL; ++j) lm = umax64(lm, key[j]);
    }
  }
  if (lane < 32 - topM) out[64 + topM + lane] = t + 1 + lane;
}

// ----------------------- sparse attention per (b,t) --------------------------
// Outputs ao as h/l bf16 planes (feeds G5's raw A staging).
__global__ __launch_bounds__(256) void attn_kernel(
    const float* __restrict__ qproj, const float* __restrict__ kvproj,
    const float* __restrict__ qiki, const int* __restrict__ idx_sel,
    const float* __restrict__ raw_delta, u16* __restrict__ aoh,
    u16* __restrict__ aol) {
  const int bt = blockIdx.x;
  const int b = bt >> 10;
  const int t = bt & 1023;
  const int tid = threadIdx.x;

  __shared__ __align__(16) float qcs[NH * DH];   // 512
  __shared__ __align__(16) float qrs[NH * DR];   // 256
  __shared__ __align__(16) float krs[KTS * DR];  // 3072
  __shared__ float scS[NH * 100];                // stride 100: no bank alias
  __shared__ int selS[KTS];
  __shared__ int offS[KTS];
  __shared__ float thetav[16], deltav[16];
  __shared__ float mu[NH * DR];

  const float* qrow = qproj + (size_t)bt * NQP;
  qcs[tid] = qrow[tid];
  qcs[256 + tid] = qrow[256 + tid];
  mu[tid] = softplusf(qrow[512 + tid]);
  if (tid < KTS) {
    int s = idx_sel[(size_t)bt * KTS + tid];
    selS[tid] = s;
    offS[tid] = s * NKV;
  }
  if (tid < 16) {
    thetav[tid] = (float)(1.0 / pow(10000.0, (double)tid / 16.0));
    float r = raw_delta[tid];
    deltav[tid] = -6.2831853071795864769f * (1.f / (1.f + expf(-r)));
  }
  __syncthreads();

  if (tid < 128) {
    int h = tid >> 4, i = tid & 15;
    float ang = (float)t * thetav[i] + deltav[i];
    float c = cosf(ang), s = sinf(ang);
    float m1 = mu[h * DR + i], m2 = mu[h * DR + 16 + i];
    qrs[h * DR + i] = m1 * c - m2 * s;
    qrs[h * DR + 16 + i] = m1 * s + m2 * c;
  }
  const float* krb = qiki + (size_t)b * L * CCW + 320;
  for (int e = tid; e < KTS * 16; e += 256) {
    int k = e >> 4, i = e & 15;
    int s = selS[k];
    float x1 = krb[(size_t)s * CCW + i];
    float x2 = krb[(size_t)s * CCW + 16 + i];
    float m1 = softplusf(x1), m2 = softplusf(x2);
    float ang = (float)k * thetav[i] + deltav[i];
    float c = cosf(ang), sn = sinf(ang);
    krs[k * DR + i] = m1 * c - m2 * sn;
    krs[k * DR + 16 + i] = m1 * sn + m2 * c;
  }
  __syncthreads();

  // ---- scores: k-major coalesced rows, uniform rope, shfl reduce ----
  const float scale = 0.10206207261596575f;  // (64+32)^-0.5
  const int h = tid >> 5;
  const int l = tid & 31;
  const float2 qv = *(const float2*)&qcs[h * DH + 2 * l];
  const float qr1 = qrs[h * DR + l];
  const float* kvb = kvproj + (size_t)b * L * NKV;
#pragma unroll 8
  for (int k = 0; k < KTS; ++k) {
    const float2 kv = *(const float2*)(kvb + offS[k] + 2 * tid);
    float p = qv.x * kv.x + qv.y * kv.y + qr1 * krs[k * DR + l];
#pragma unroll
    for (int off = 16; off > 0; off >>= 1) p += __shfl_xor(p, off, 32);
    if (l == 0) scS[h * 100 + k] = p * scale;
  }
  __syncthreads();

  // ---- softmax: 32-lane group per head ----
  {
    float s0 = scS[h * 100 + l], s1 = scS[h * 100 + l + 32],
          s2 = scS[h * 100 + l + 64];
    float mx = fmaxf(fmaxf(s0, s1), s2);
#pragma unroll
    for (int off = 16; off > 0; off >>= 1) mx = fmaxf(mx, __shfl_xor(mx, off, 32));
    float e0 = expf(s0 - mx), e1 = expf(s1 - mx), e2 = expf(s2 - mx);
    float sum = e0 + e1 + e2;
#pragma unroll
    for (int off = 16; off > 0; off >>= 1) sum += __shfl_xor(sum, off, 32);
    float inv = 1.f / sum;
    scS[h * 100 + l] = e0 * inv;
    scS[h * 100 + l + 32] = e1 * inv;
    scS[h * 100 + l + 64] = e2 * inv;
  }
  __syncthreads();

  // ---- PV ----
  float2 acc = make_float2(0.f, 0.f);
#pragma unroll 4
  for (int k = 0; k < KTS; ++k) {
    const float2 v = *(const float2*)(kvb + offS[k] + 512 + 2 * tid);
    const float w = scS[h * 100 + k];
    acc.x += w * v.x;
    acc.y += w * v.y;
  }
  u16 hx = bf16_rn(acc.x), hy = bf16_rn(acc.y);
  u16 lx = bf16_rn(acc.x - bf16_tof(hx)), ly = bf16_rn(acc.y - bf16_tof(hy));
  const size_t o = (size_t)bt * 512 + 2 * tid;
  *(u32*)(aoh + o) = (u32)hx | ((u32)hy << 16);
  *(u32*)(aol + o) = (u32)lx | ((u32)ly << 16);
}

// -----------------------------------------------------------------------------
extern "C" void kernel_launch(void* const* d_in, const int* in_sizes, int n_in,
                              void* d_out, int out_size, void* d_ws, size_t ws_size,
                              hipStream_t stream) {
  const float* x      = (const float*)d_in[0];
  const float* W_dkv  = (const float*)d_in[1];
  const float* W_uk   = (const float*)d_in[2];
  const float* W_uv   = (const float*)d_in[3];
  const float* W_dq   = (const float*)d_in[4];
  const float* W_uq   = (const float*)d_in[5];
  const float* W_qr   = (const float*)d_in[6];
  const float* W_kr   = (const float*)d_in[7];
  const float* W_out  = (const float*)d_in[8];
  const float* idx_wq = (const float*)d_in[9];
  const float* idx_wk = (const float*)d_in[10];
  const float* idx_w  = (const float*)d_in[11];
  const float* raw_dl = (const float*)d_in[12];
  float* out = (float*)d_out;

  const int M = 2 * L;  // 2048
  // ---- workspace (u16 planes first, then fp32) ----
  u16* BxT_h  = (u16*)d_ws;                       // 1152*1024 x3
  u16* BxT_m  = BxT_h + 1152 * 1024;
  u16* BxT_l  = BxT_m + 1152 * 1024;
  u16* BkvT_h = BxT_l + 1152 * 1024;              // 1024*256 x2
  u16* BkvT_l = BkvT_h + 1024 * 256;
  u16* BqT_h  = BkvT_l + 1024 * 256;              // 768*512 x2
  u16* BqT_l  = BqT_h + 768 * 512;
  u16* WoT_h  = BqT_l + 768 * 512;                // 1024*512 x2
  u16* WoT_l  = WoT_h + 1024 * 512;
  u16* Xh     = WoT_l + 1024 * 512;               // 2048*1024 x3
  u16* Xm     = Xh + (size_t)M * 1024;
  u16* Xl     = Xm + (size_t)M * 1024;
  u16* XPh    = Xl + (size_t)M * 1024;            // 2048*768 x2
  u16* XPl    = XPh + (size_t)M * 768;
  u16* AOh    = XPl + (size_t)M * 768;            // 2048*512 x2
  u16* AOl    = AOh + (size_t)M * 512;
  float* qiki   = (float*)(AOl + (size_t)M * 512);  // 2048*352
  float* kvproj = qiki + (size_t)M * CCW;           // 2048*1024
  float* qproj  = kvproj + (size_t)M * NKV;         // 2048*768
  int* sel      = (int*)(qproj + (size_t)M * NQP);  // 2048*96

  dim3 blk(256);
  TSrc z = {nullptr, 0, 0};
  // ---- weight prep ----
  {
    TSrc a = {W_dkv, 0, 256}, bq = {W_dq, 256, 512}, c = {idx_wq, 768, 256},
         d = {idx_wk, 1024, 64}, e = {W_kr, 1088, 32};
    hipLaunchKernelGGL(wsplit, dim3(1152 / 32, 1024 / 32), blk, 0, stream,
                       a, bq, c, d, e, 1024, BxT_h, BxT_m, BxT_l);
  }
  {
    TSrc a = {W_uk, 0, 512}, bq = {W_uv, 512, 512};
    hipLaunchKernelGGL(wsplit, dim3(1024 / 32, 256 / 32), blk, 0, stream,
                       a, bq, z, z, z, 256, BkvT_h, (u16*)nullptr, BkvT_l);
  }
  {
    TSrc a = {W_uq, 0, 512}, bq = {W_qr, 512, 256};
    hipLaunchKernelGGL(wsplit, dim3(768 / 32, 512 / 32), blk, 0, stream,
                       a, bq, z, z, z, 512, BqT_h, (u16*)nullptr, BqT_l);
  }
  {
    TSrc a = {W_out, 0, 1024};
    hipLaunchKernelGGL(wsplit, dim3(1024 / 32, 512 / 32), blk, 0, stream,
                       a, z, z, z, z, 512, WoT_h, (u16*)nullptr, WoT_l);
  }
  hipLaunchKernelGGL(xsplit, dim3(M * 1024 / (256 * 4)), blk, 0, stream,
                     x, Xh, Xm, Xl);
  // ---- G1a: cols 0..768 (c_kv|c_q), x2, plane output ----
  {
    GArg g = {Xh, Xm, nullptr, BxT_h, BxT_m, nullptr,
              nullptr, XPh, XPl, 1024, 768, 1024, 6};
    hipLaunchKernelGGL((mfma_gemm<2, 1>), dim3(6, M / 128, 1), blk, 0, stream,
                       g, g);
  }
  // ---- G1b: cols 768..1152 (qi|ki|kr), x3, fp32 compact output ----
  {
    GArg g = {Xh, Xm, Xl, BxT_h + 768 * 1024, BxT_m + 768 * 1024,
              BxT_l + 768 * 1024, qiki, nullptr, nullptr, 1024, CCW, 1024, 3};
    hipLaunchKernelGGL((mfma_gemm<3, 2>), dim3(3, M / 128, 1), blk, 0, stream,
                       g, g);
  }
  hipLaunchKernelGGL(indexer_topk, dim3(M / 4), blk, 0, stream, qiki, idx_w, sel);
  // ---- G2 (kvproj, K=256) + G3 (qproj, K=512) fused via z ----
  {
    GArg g2 = {XPh, XPl, nullptr, BkvT_h, BkvT_l, nullptr,
               kvproj, nullptr, nullptr, 768, 1024, 256, 8};
    GArg g3 = {XPh + 256, XPl + 256, nullptr, BqT_h, BqT_l, nullptr,
               qproj, nullptr, nullptr, 768, 768, 512, 6};
    hipLaunchKernelGGL((mfma_gemm<2, 0>), dim3(8, M / 128, 2), blk, 0, stream,
                       g2, g3);
  }
  hipLaunchKernelGGL(attn_kernel, dim3(M), blk, 0, stream,
                     qproj, kvproj, qiki, sel, raw_dl, AOh, AOl);
  // ---- G5: out = ao @ W_out ----
  {
    GArg g = {AOh, AOl, nullptr, WoT_h, WoT_l, nullptr,
              out, nullptr, nullptr, 512, 1024, 512, 8};
    hipLaunchKernelGGL((mfma_gemm<2, 0>), dim3(8, M / 128, 1), blk, 0, stream,
                       g, g);
  }
}

// Round 7
// 382.792 us; speedup vs baseline: 1.0975x; 1.0975x over previous
//
#include <hip/hip_runtime.h>
#include <math.h>

typedef unsigned short u16;
typedef unsigned int u32;
typedef unsigned long long u64;
typedef __attribute__((ext_vector_type(8))) short bf16x8;
typedef __attribute__((ext_vector_type(4))) float f32x4;

#define L      1024
#define NH     8
#define DH     64
#define DR     32
#define KTS    96
#define LWIN   64
#define NKV    1024   // [kc 512 | vc 512]
#define NQP    768    // [qc 512 | qrp 256]

__device__ __forceinline__ u16 bf16_rn(float x) {
  unsigned u = __float_as_uint(x);
  return (u16)((u + 0x7fffu + ((u >> 16) & 1u)) >> 16);
}
__device__ __forceinline__ float bf16_tof(u16 h) {
  return __uint_as_float(((unsigned)h) << 16);
}
__device__ __forceinline__ float softplusf(float x) {
  return fmaxf(x, 0.f) + log1pf(expf(-fabsf(x)));
}
__device__ __forceinline__ f32x4 mfma16(bf16x8 a, bf16x8 b, f32x4 c) {
  return __builtin_amdgcn_mfma_f32_16x16x32_bf16(a, b, c, 0, 0, 0);
}
__device__ __forceinline__ u64 pack4(u16 a, u16 b, u16 c, u16 d) {
  return (u64)a | ((u64)b << 16) | ((u64)c << 32) | ((u64)d << 48);
}
__device__ __forceinline__ u64 umax64(u64 a, u64 b) { return a > b ? a : b; }

// ---------------- weight transpose + bf16 split ([K][N] -> [N][K] planes) ----
struct TSrc { const float* p; int n0, w; };

__global__ __launch_bounds__(256) void wsplit(
    TSrc s0, TSrc s1, TSrc s2, TSrc s3, TSrc s4,
    int K, u16* __restrict__ Ph, u16* __restrict__ Pm, u16* __restrict__ Pl) {
  __shared__ float tile[32][33];
  const int k0 = blockIdx.y * 32, n0 = blockIdx.x * 32;
  const int tid = threadIdx.x;
  const float* sp = nullptr; int off = 0, w = 0;
  if (s0.p && n0 >= s0.n0 && n0 < s0.n0 + s0.w) { sp = s0.p; off = s0.n0; w = s0.w; }
  else if (s1.p && n0 >= s1.n0 && n0 < s1.n0 + s1.w) { sp = s1.p; off = s1.n0; w = s1.w; }
  else if (s2.p && n0 >= s2.n0 && n0 < s2.n0 + s2.w) { sp = s2.p; off = s2.n0; w = s2.w; }
  else if (s3.p && n0 >= s3.n0 && n0 < s3.n0 + s3.w) { sp = s3.p; off = s3.n0; w = s3.w; }
  else if (s4.p && n0 >= s4.n0 && n0 < s4.n0 + s4.w) { sp = s4.p; off = s4.n0; w = s4.w; }
  {
    const int kl = tid >> 3, n4 = (tid & 7) * 4;
    float4 v = make_float4(0.f, 0.f, 0.f, 0.f);
    if (sp) v = *(const float4*)(sp + (size_t)(k0 + kl) * w + (n0 - off) + n4);
    tile[kl][n4 + 0] = v.x; tile[kl][n4 + 1] = v.y;
    tile[kl][n4 + 2] = v.z; tile[kl][n4 + 3] = v.w;
  }
  __syncthreads();
  const int nl = tid >> 3, k4 = (tid & 7) * 4;
  u16 h[4], m[4], lo[4];
#pragma unroll
  for (int j = 0; j < 4; ++j) {
    float x = tile[k4 + j][nl];
    u16 hh = bf16_rn(x); float r = x - bf16_tof(hh);
    h[j] = hh;
    if (Pm) { u16 mm = bf16_rn(r); r = r - bf16_tof(mm); m[j] = mm; }
    lo[j] = bf16_rn(r);
  }
  const size_t o = (size_t)(n0 + nl) * K + k0 + k4;
  *(u64*)(Ph + o) = pack4(h[0], h[1], h[2], h[3]);
  if (Pm) *(u64*)(Pm + o) = pack4(m[0], m[1], m[2], m[3]);
  *(u64*)(Pl + o) = pack4(lo[0], lo[1], lo[2], lo[3]);
}

// ---------------- x -> h/m/l planes (row-major, elementwise) -----------------
__global__ __launch_bounds__(256) void xsplit(
    const float* __restrict__ x, u16* __restrict__ Xh, u16* __restrict__ Xm,
    u16* __restrict__ Xl) {
  const int i = (blockIdx.x * 256 + threadIdx.x) * 4;
  float4 v = *(const float4*)(x + i);
  float e[4] = {v.x, v.y, v.z, v.w};
  u16 h[4], m[4], lo[4];
#pragma unroll
  for (int j = 0; j < 4; ++j) {
    u16 hh = bf16_rn(e[j]); float r = e[j] - bf16_tof(hh);
    h[j] = hh;
    u16 mm = bf16_rn(r); r = r - bf16_tof(mm); m[j] = mm;
    lo[j] = bf16_rn(r);
  }
  *(u64*)(Xh + i) = pack4(h[0], h[1], h[2], h[3]);
  *(u64*)(Xm + i) = pack4(m[0], m[1], m[2], m[3]);
  *(u64*)(Xl + i) = pack4(lo[0], lo[1], lo[2], lo[3]);
}

// ---------------- bf16-split MFMA GEMM (all-plane staging) -------------------
// OUT: 0 = fp32 C; 1 = h/l u16 planes Ch/Cl;
//      2 = indexer epilogue (qi->x3 planes rows bt*4+h, ki->x3 planes, kr fp32)
//      3 = I epilogue: I[t][s] = sum_j IW[j]*relu(acc_j)
struct GArg {
  const u16 *A0, *A1, *A2, *B0, *B1, *B2;
  float* C; u16 *Ch, *Cl;
  u16 *Qh, *Qm, *Ql, *Kh, *Km, *Kl; float* KR; const float* IW;
  int lda, ldc, K, nbn;
};

template <int NS, int OUT>
__global__ __launch_bounds__(256) void mfma_gemm(GArg g0, GArg g1) {
  GArg g = (blockIdx.z == 0) ? g0 : g1;
  if ((int)blockIdx.x >= g.nbn) return;
  __shared__ u16 Al[NS * 5120];
  __shared__ u16 Bl[NS * 5120];
  const int tid = threadIdx.x;
  const int l = tid & 63, w = tid >> 6;
  const int wr = w >> 1, wc = w & 1;
  const int l15 = l & 15, l4 = l >> 4;
  const int bm = blockIdx.y * 128, bn = blockIdx.x * 128;
  const int ar2 = tid >> 1, akc = (tid & 1) * 16;
  const int brr = tid >> 2, bkc = (tid & 3) * 8;

  f32x4 acc[4][4];
#pragma unroll
  for (int i = 0; i < 4; ++i)
#pragma unroll
    for (int j = 0; j < 4; ++j) acc[i][j] = (f32x4){0.f, 0.f, 0.f, 0.f};

  for (int k0 = 0; k0 < g.K; k0 += 32) {
#pragma unroll
    for (int p = 0; p < NS; ++p) {
      const u16* Ap = (p == 0) ? g.A0 : (p == 1 ? g.A1 : g.A2);
      const size_t ab = (size_t)(bm + ar2) * g.lda + k0 + akc;
      *(uint4*)&Al[p * 5120 + ar2 * 40 + akc] = *(const uint4*)(Ap + ab);
      *(uint4*)&Al[p * 5120 + ar2 * 40 + akc + 8] = *(const uint4*)(Ap + ab + 8);
      const u16* Bp = (p == 0) ? g.B0 : (p == 1 ? g.B1 : g.B2);
#pragma unroll
      for (int i = 0; i < 2; ++i) {
        const int row = brr + i * 64;
        *(uint4*)&Bl[p * 5120 + row * 40 + bkc] =
            *(const uint4*)(Bp + (size_t)(bn + row) * g.K + k0 + bkc);
      }
    }
    __syncthreads();
    bf16x8 af[NS][4], bf[NS][4];
#pragma unroll
    for (int f = 0; f < 4; ++f) {
      const int arow = wr * 64 + f * 16 + l15;
      const int brow = wc * 64 + f * 16 + l15;
#pragma unroll
      for (int p = 0; p < NS; ++p) {
        af[p][f] = *(const bf16x8*)&Al[p * 5120 + arow * 40 + l4 * 8];
        bf[p][f] = *(const bf16x8*)&Bl[p * 5120 + brow * 40 + l4 * 8];
      }
    }
#pragma unroll
    for (int fm = 0; fm < 4; ++fm)
#pragma unroll
      for (int fn = 0; fn < 4; ++fn) {
        f32x4 c = acc[fm][fn];
        c = mfma16(af[0][fm], bf[0][fn], c);
        c = mfma16(af[0][fm], bf[1][fn], c);
        c = mfma16(af[1][fm], bf[0][fn], c);
        if (NS == 3) {
          c = mfma16(af[0][fm], bf[2][fn], c);
          c = mfma16(af[2][fm], bf[0][fn], c);
          c = mfma16(af[1][fm], bf[1][fn], c);
        }
        acc[fm][fn] = c;
      }
    __syncthreads();
  }
  if (OUT == 3) {
    const float w0 = g.IW[0], w1 = g.IW[1], w2 = g.IW[2], w3 = g.IW[3];
#pragma unroll
    for (int fm = 0; fm < 4; ++fm) {
      const int tt = (bm >> 2) + wr * 16 + fm * 4 + l4;
#pragma unroll
      for (int fn = 0; fn < 4; ++fn) {
        const int col = bn + wc * 64 + fn * 16 + l15;
        const f32x4 a = acc[fm][fn];
        float v = w0 * fmaxf(a[0], 0.f) + w1 * fmaxf(a[1], 0.f)
                + w2 * fmaxf(a[2], 0.f) + w3 * fmaxf(a[3], 0.f);
        g.C[(size_t)tt * g.ldc + col] = v;
      }
    }
    return;
  }
#pragma unroll
  for (int fm = 0; fm < 4; ++fm)
#pragma unroll
    for (int j = 0; j < 4; ++j) {
      const int row = bm + wr * 64 + fm * 16 + l4 * 4 + j;
#pragma unroll
      for (int fn = 0; fn < 4; ++fn) {
        const int col = bn + wc * 64 + fn * 16 + l15;
        const float val = acc[fm][fn][j];
        if (OUT == 0) {
          g.C[(size_t)row * g.ldc + col] = val;
        } else if (OUT == 1) {
          u16 hh = bf16_rn(val);
          g.Ch[(size_t)row * g.ldc + col] = hh;
          g.Cl[(size_t)row * g.ldc + col] = bf16_rn(val - bf16_tof(hh));
        } else {  // OUT == 2: local cols [qi 256 | ki 64 | kr 32 | pad 32]
          u16 hh = bf16_rn(val);
          float r = val - bf16_tof(hh);
          u16 mm = bf16_rn(r);
          u16 ll = bf16_rn(r - bf16_tof(mm));
          if (col < 256) {
            const size_t o = ((size_t)row * 4 + (col >> 6)) * 64 + (col & 63);
            g.Qh[o] = hh; g.Qm[o] = mm; g.Ql[o] = ll;
          } else if (col < 320) {
            const size_t o = (size_t)row * 64 + (col - 256);
            g.Kh[o] = hh; g.Km[o] = mm; g.Kl[o] = ll;
          } else if (col < 352) {
            g.KR[(size_t)row * 32 + (col - 320)] = val;
          }
        }
      }
    }
}

// ------------- TokenSelector top-k over precomputed I[b][t][s] ---------------
// One wave per row; 16 reg keys/lane; exact jax.lax.top_k ordering.
__global__ __launch_bounds__(256) void topk2(
    const float* __restrict__ IM, int* __restrict__ idx_sel) {
  const int wave = threadIdx.x >> 6, lane = threadIdx.x & 63;
  const int bt = blockIdx.x * 4 + wave;
  const int b = bt >> 10, t = bt & 1023;
  int* out = idx_sel + (size_t)bt * KTS;
  if (t < LWIN) {
    out[lane] = lane;
    if (lane < 32) out[64 + lane] = 64 + lane;
    return;
  }
  out[lane] = t - 63 + lane;
  const int nf = t - 63;
  const float* Irow = IM + ((size_t)b << 20) + ((size_t)t << 10);
  u64 key[16];
#pragma unroll
  for (int gq = 0; gq < 4; ++gq) {
    const int s0 = gq * 256 + lane * 4;
    float4 v = make_float4(0.f, 0.f, 0.f, 0.f);
    if (s0 < nf) v = *(const float4*)(Irow + s0);
    float e[4] = {v.x, v.y, v.z, v.w};
#pragma unroll
    for (int c = 0; c < 4; ++c) {
      u64 k = 0ull;
      const int s = s0 + c;
      if (s < nf) {
        unsigned ib = __float_as_uint(e[c]);
        if (ib == 0x80000000u) ib = 0u;
        ib = (ib & 0x80000000u) ? ~ib : (ib | 0x80000000u);
        k = ((u64)ib << 32) | (u64)(0xFFFFFFFFu - (unsigned)s);
      }
      key[gq * 4 + c] = k;
    }
  }
  u64 lm = key[0];
#pragma unroll
  for (int j = 1; j < 16; ++j) lm = umax64(lm, key[j]);
  const int topM = nf < 32 ? nf : 32;
  for (int it = 0; it < topM; ++it) {
    u64 m = lm;
#pragma unroll
    for (int off = 32; off > 0; off >>= 1) m = umax64(m, __shfl_xor(m, off));
    if (lane == 0)
      out[64 + it] = (int)(0xFFFFFFFFu - (unsigned)(m & 0xFFFFFFFFull));
    if (lm == m) {
#pragma unroll
      for (int j = 0; j < 16; ++j)
        if (key[j] == m) key[j] = 0ull;
      lm = key[0];
#pragma unroll
      for (int j = 1; j < 16; ++j) lm = umax64(lm, key[j]);
    }
  }
  if (lane < 32 - topM) out[64 + topM + lane] = t + 1 + lane;
}

// ----------------------- sparse attention per (b,t) --------------------------
// XCD-chunked swizzle: each XCD owns 256 consecutive tokens -> gathered K/V
// rows stay L2-resident.
__global__ __launch_bounds__(256) void attn_kernel(
    const float* __restrict__ qproj, const float* __restrict__ kvproj,
    const float* __restrict__ krc, const int* __restrict__ idx_sel,
    const float* __restrict__ raw_delta, u16* __restrict__ aoh,
    u16* __restrict__ aol) {
  const int bt = ((blockIdx.x & 7) << 8) | (blockIdx.x >> 3);
  const int b = bt >> 10;
  const int t = bt & 1023;
  const int tid = threadIdx.x;

  __shared__ __align__(16) float qcs[NH * DH];
  __shared__ __align__(16) float qrs[NH * DR];
  __shared__ __align__(16) float krs[KTS * DR];
  __shared__ float scS[NH * 100];
  __shared__ int selS[KTS];
  __shared__ int offS[KTS];
  __shared__ float thetav[16], deltav[16];
  __shared__ float mu[NH * DR];

  const float* qrow = qproj + (size_t)bt * NQP;
  qcs[tid] = qrow[tid];
  qcs[256 + tid] = qrow[256 + tid];
  mu[tid] = softplusf(qrow[512 + tid]);
  if (tid < KTS) {
    int s = idx_sel[(size_t)bt * KTS + tid];
    selS[tid] = s;
    offS[tid] = s * NKV;
  }
  if (tid < 16) {
    thetav[tid] = (float)(1.0 / pow(10000.0, (double)tid / 16.0));
    float r = raw_delta[tid];
    deltav[tid] = -6.2831853071795864769f * (1.f / (1.f + expf(-r)));
  }
  __syncthreads();

  if (tid < 128) {
    int h = tid >> 4, i = tid & 15;
    float ang = (float)t * thetav[i] + deltav[i];
    float c = cosf(ang), s = sinf(ang);
    float m1 = mu[h * DR + i], m2 = mu[h * DR + 16 + i];
    qrs[h * DR + i] = m1 * c - m2 * s;
    qrs[h * DR + 16 + i] = m1 * s + m2 * c;
  }
  const float* krb = krc + (size_t)b * L * 32;
  for (int e = tid; e < KTS * 16; e += 256) {
    int k = e >> 4, i = e & 15;
    int s = selS[k];
    float x1 = krb[(size_t)s * 32 + i];
    float x2 = krb[(size_t)s * 32 + 16 + i];
    float m1 = softplusf(x1), m2 = softplusf(x2);
    float ang = (float)k * thetav[i] + deltav[i];
    float c = cosf(ang), sn = sinf(ang);
    krs[k * DR + i] = m1 * c - m2 * sn;
    krs[k * DR + 16 + i] = m1 * sn + m2 * c;
  }
  __syncthreads();

  const float scale = 0.10206207261596575f;  // (64+32)^-0.5
  const int h = tid >> 5;
  const int l = tid & 31;
  const float2 qv = *(const float2*)&qcs[h * DH + 2 * l];
  const float qr1 = qrs[h * DR + l];
  const float* kvb = kvproj + (size_t)b * L * NKV;
#pragma unroll 8
  for (int k = 0; k < KTS; ++k) {
    const float2 kv = *(const float2*)(kvb + offS[k] + 2 * tid);
    float p = qv.x * kv.x + qv.y * kv.y + qr1 * krs[k * DR + l];
#pragma unroll
    for (int off = 16; off > 0; off >>= 1) p += __shfl_xor(p, off, 32);
    if (l == 0) scS[h * 100 + k] = p * scale;
  }
  __syncthreads();

  {
    float s0 = scS[h * 100 + l], s1 = scS[h * 100 + l + 32],
          s2 = scS[h * 100 + l + 64];
    float mx = fmaxf(fmaxf(s0, s1), s2);
#pragma unroll
    for (int off = 16; off > 0; off >>= 1) mx = fmaxf(mx, __shfl_xor(mx, off, 32));
    float e0 = expf(s0 - mx), e1 = expf(s1 - mx), e2 = expf(s2 - mx);
    float sum = e0 + e1 + e2;
#pragma unroll
    for (int off = 16; off > 0; off >>= 1) sum += __shfl_xor(sum, off, 32);
    float inv = 1.f / sum;
    scS[h * 100 + l] = e0 * inv;
    scS[h * 100 + l + 32] = e1 * inv;
    scS[h * 100 + l + 64] = e2 * inv;
  }
  __syncthreads();

  float2 acc = make_float2(0.f, 0.f);
#pragma unroll 4
  for (int k = 0; k < KTS; ++k) {
    const float2 v = *(const float2*)(kvb + offS[k] + 512 + 2 * tid);
    const float w = scS[h * 100 + k];
    acc.x += w * v.x;
    acc.y += w * v.y;
  }
  u16 hx = bf16_rn(acc.x), hy = bf16_rn(acc.y);
  u16 lx = bf16_rn(acc.x - bf16_tof(hx)), ly = bf16_rn(acc.y - bf16_tof(hy));
  const size_t o = (size_t)bt * 512 + 2 * tid;
  *(u32*)(aoh + o) = (u32)hx | ((u32)hy << 16);
  *(u32*)(aol + o) = (u32)lx | ((u32)ly << 16);
}

// -----------------------------------------------------------------------------
extern "C" void kernel_launch(void* const* d_in, const int* in_sizes, int n_in,
                              void* d_out, int out_size, void* d_ws, size_t ws_size,
                              hipStream_t stream) {
  const float* x      = (const float*)d_in[0];
  const float* W_dkv  = (const float*)d_in[1];
  const float* W_uk   = (const float*)d_in[2];
  const float* W_uv   = (const float*)d_in[3];
  const float* W_dq   = (const float*)d_in[4];
  const float* W_uq   = (const float*)d_in[5];
  const float* W_qr   = (const float*)d_in[6];
  const float* W_kr   = (const float*)d_in[7];
  const float* W_out  = (const float*)d_in[8];
  const float* idx_wq = (const float*)d_in[9];
  const float* idx_wk = (const float*)d_in[10];
  const float* idx_w  = (const float*)d_in[11];
  const float* raw_dl = (const float*)d_in[12];
  float* out = (float*)d_out;

  const int M = 2 * L;  // 2048
  // ---- workspace ----
  u16* BxT_h  = (u16*)d_ws;                       // 1152*1024 x3
  u16* BxT_m  = BxT_h + 1152 * 1024;
  u16* BxT_l  = BxT_m + 1152 * 1024;
  u16* BkvT_h = BxT_l + 1152 * 1024;              // 1024*256 x2
  u16* BkvT_l = BkvT_h + 1024 * 256;
  u16* BqT_h  = BkvT_l + 1024 * 256;              // 768*512 x2
  u16* BqT_l  = BqT_h + 768 * 512;
  u16* WoT_h  = BqT_l + 768 * 512;                // 1024*512 x2
  u16* WoT_l  = WoT_h + 1024 * 512;
  u16* Xh     = WoT_l + 1024 * 512;               // 2048*1024 x3 (dead after G1b)
  u16* Xm     = Xh + (size_t)M * 1024;
  u16* Xl     = Xm + (size_t)M * 1024;
  u16* XPh    = Xl + (size_t)M * 1024;            // 2048*768 x2
  u16* XPl    = XPh + (size_t)M * 768;
  u16* AOh    = XPl + (size_t)M * 768;            // 2048*512 x2
  u16* AOl    = AOh + (size_t)M * 512;
  u16* Qih    = AOl + (size_t)M * 512;            // 8192*64 x3 (qi, rows bt*4+h)
  u16* Qim    = Qih + (size_t)M * 4 * 64;
  u16* Qil    = Qim + (size_t)M * 4 * 64;
  u16* Kih    = Qil + (size_t)M * 4 * 64;         // 2048*64 x3
  u16* Kim    = Kih + (size_t)M * 64;
  u16* Kil    = Kim + (size_t)M * 64;
  float* krc    = (float*)(Kil + (size_t)M * 64); // 2048*32
  float* kvproj = krc + (size_t)M * 32;           // 2048*1024
  float* qproj  = kvproj + (size_t)M * NKV;       // 2048*768
  int* sel      = (int*)(qproj + (size_t)M * NQP);
  float* IM     = (float*)Xh;                     // 2*1024*1024 (aliases X planes)

  dim3 blk(256);
  TSrc z = {nullptr, 0, 0};
  GArg Z = {};
  // ---- weight prep ----
  {
    TSrc a = {W_dkv, 0, 256}, bq = {W_dq, 256, 512}, c = {idx_wq, 768, 256},
         d = {idx_wk, 1024, 64}, e = {W_kr, 1088, 32};
    hipLaunchKernelGGL(wsplit, dim3(1152 / 32, 1024 / 32), blk, 0, stream,
                       a, bq, c, d, e, 1024, BxT_h, BxT_m, BxT_l);
  }
  {
    TSrc a = {W_uk, 0, 512}, bq = {W_uv, 512, 512};
    hipLaunchKernelGGL(wsplit, dim3(1024 / 32, 256 / 32), blk, 0, stream,
                       a, bq, z, z, z, 256, BkvT_h, (u16*)nullptr, BkvT_l);
  }
  {
    TSrc a = {W_uq, 0, 512}, bq = {W_qr, 512, 256};
    hipLaunchKernelGGL(wsplit, dim3(768 / 32, 512 / 32), blk, 0, stream,
                       a, bq, z, z, z, 512, BqT_h, (u16*)nullptr, BqT_l);
  }
  {
    TSrc a = {W_out, 0, 1024};
    hipLaunchKernelGGL(wsplit, dim3(1024 / 32, 512 / 32), blk, 0, stream,
                       a, z, z, z, z, 512, WoT_h, (u16*)nullptr, WoT_l);
  }
  hipLaunchKernelGGL(xsplit, dim3(M * 1024 / (256 * 4)), blk, 0, stream,
                     x, Xh, Xm, Xl);
  // ---- G1a: cols 0..768 (c_kv|c_q), x2, plane output ----
  {
    GArg g = Z;
    g.A0 = Xh; g.A1 = Xm; g.B0 = BxT_h; g.B1 = BxT_m;
    g.Ch = XPh; g.Cl = XPl; g.lda = 1024; g.ldc = 768; g.K = 1024; g.nbn = 6;
    hipLaunchKernelGGL((mfma_gemm<2, 1>), dim3(6, M / 128, 1), blk, 0, stream,
                       g, g);
  }
  // ---- G1b: cols 768..1152 (qi|ki|kr), x3, indexer epilogue ----
  {
    GArg g = Z;
    g.A0 = Xh; g.A1 = Xm; g.A2 = Xl;
    g.B0 = BxT_h + 768 * 1024; g.B1 = BxT_m + 768 * 1024;
    g.B2 = BxT_l + 768 * 1024;
    g.Qh = Qih; g.Qm = Qim; g.Ql = Qil;
    g.Kh = Kih; g.Km = Kim; g.Kl = Kil; g.KR = krc;
    g.lda = 1024; g.ldc = 0; g.K = 1024; g.nbn = 3;
    hipLaunchKernelGGL((mfma_gemm<3, 2>), dim3(3, M / 128, 1), blk, 0, stream,
                       g, g);
  }
  // ---- I-GEMM: I[b][t][s] = sum_h w_h relu(qi_h(t).ki(s)), per-b via z ----
  {
    GArg g0 = Z, g1 = Z;
    g0.A0 = Qih; g0.A1 = Qim; g0.A2 = Qil;
    g0.B0 = Kih; g0.B1 = Kim; g0.B2 = Kil;
    g0.C = IM; g0.IW = idx_w;
    g0.lda = 64; g0.ldc = 1024; g0.K = 64; g0.nbn = 8;
    g1 = g0;
    g1.A0 = Qih + 4096 * 64; g1.A1 = Qim + 4096 * 64; g1.A2 = Qil + 4096 * 64;
    g1.B0 = Kih + 1024 * 64; g1.B1 = Kim + 1024 * 64; g1.B2 = Kil + 1024 * 64;
    g1.C = IM + 1024 * 1024;
    hipLaunchKernelGGL((mfma_gemm<3, 3>), dim3(8, 32, 2), blk, 0, stream,
                       g0, g1);
  }
  hipLaunchKernelGGL(topk2, dim3(M / 4), blk, 0, stream, IM, sel);
  // ---- G2 (kvproj, K=256) + G3 (qproj, K=512) fused via z ----
  {
    GArg g2 = Z, g3 = Z;
    g2.A0 = XPh; g2.A1 = XPl; g2.B0 = BkvT_h; g2.B1 = BkvT_l;
    g2.C = kvproj; g2.lda = 768; g2.ldc = 1024; g2.K = 256; g2.nbn = 8;
    g3.A0 = XPh + 256; g3.A1 = XPl + 256; g3.B0 = BqT_h; g3.B1 = BqT_l;
    g3.C = qproj; g3.lda = 768; g3.ldc = 768; g3.K = 512; g3.nbn = 6;
    hipLaunchKernelGGL((mfma_gemm<2, 0>), dim3(8, M / 128, 2), blk, 0, stream,
                       g2, g3);
  }
  hipLaunchKernelGGL(attn_kernel, dim3(M), blk, 0, stream,
                     qproj, kvproj, krc, sel, raw_dl, AOh, AOl);
  // ---- G5: out = ao @ W_out ----
  {
    GArg g = Z;
    g.A0 = AOh; g.A1 = AOl; g.B0 = WoT_h; g.B1 = WoT_l;
    g.C = out; g.lda = 512; g.ldc = 1024; g.K = 512; g.nbn = 8;
    hipLaunchKernelGGL((mfma_gemm<2, 0>), dim3(8, M / 128, 1), blk, 0, stream,
                       g, g);
  }
}

// Round 8
// 319.761 us; speedup vs baseline: 1.3139x; 1.1971x over previous
//
#include <hip/hip_runtime.h>
#include <math.h>

typedef unsigned short u16;
typedef unsigned int u32;
typedef unsigned long long u64;
typedef _Float16 f16;
typedef __attribute__((ext_vector_type(8))) _Float16 f16x8;
typedef __attribute__((ext_vector_type(4))) float f32x4;

#define L      1024
#define NH     8
#define DH     64
#define DR     32
#define KTS    96
#define LWIN   64
#define NKV    1024   // [kc 512 | vc 512]
#define NQP    768    // [qc 512 | qrp 256]

__device__ __forceinline__ float softplusf(float x) {
  return fmaxf(x, 0.f) + log1pf(expf(-fabsf(x)));
}
__device__ __forceinline__ f32x4 mf16(f16x8 a, f16x8 b, f32x4 c) {
  return __builtin_amdgcn_mfma_f32_16x16x32_f16(a, b, c, 0, 0, 0);
}
__device__ __forceinline__ u64 pack4(u16 a, u16 b, u16 c, u16 d) {
  return (u64)a | ((u64)b << 16) | ((u64)c << 32) | ((u64)d << 48);
}
__device__ __forceinline__ u64 umax64(u64 a, u64 b) { return a > b ? a : b; }
__device__ __forceinline__ void f16split(float x, u16& h, u16& l) {
  f16 hh = (f16)x;
  float r = x - (float)hh;
  f16 ll = (f16)r;
  h = *(u16*)&hh; l = *(u16*)&ll;
}
__device__ __forceinline__ u16 f16bits(float x) {
  f16 hh = (f16)x;
  return *(u16*)&hh;
}

// ---------------- weight transpose + fp16 split ([K][N] -> [N][K] planes) ----
struct TSrc { const float* p; int n0, w; };

__global__ __launch_bounds__(256) void wsplit(
    TSrc s0, TSrc s1, TSrc s2, TSrc s3, TSrc s4,
    int K, u16* __restrict__ Ph, u16* __restrict__ Pl) {
  __shared__ float tile[32][33];
  const int k0 = blockIdx.y * 32, n0 = blockIdx.x * 32;
  const int tid = threadIdx.x;
  const float* sp = nullptr; int off = 0, w = 0;
  if (s0.p && n0 >= s0.n0 && n0 < s0.n0 + s0.w) { sp = s0.p; off = s0.n0; w = s0.w; }
  else if (s1.p && n0 >= s1.n0 && n0 < s1.n0 + s1.w) { sp = s1.p; off = s1.n0; w = s1.w; }
  else if (s2.p && n0 >= s2.n0 && n0 < s2.n0 + s2.w) { sp = s2.p; off = s2.n0; w = s2.w; }
  else if (s3.p && n0 >= s3.n0 && n0 < s3.n0 + s3.w) { sp = s3.p; off = s3.n0; w = s3.w; }
  else if (s4.p && n0 >= s4.n0 && n0 < s4.n0 + s4.w) { sp = s4.p; off = s4.n0; w = s4.w; }
  {
    const int kl = tid >> 3, n4 = (tid & 7) * 4;
    float4 v = make_float4(0.f, 0.f, 0.f, 0.f);
    if (sp) v = *(const float4*)(sp + (size_t)(k0 + kl) * w + (n0 - off) + n4);
    tile[kl][n4 + 0] = v.x; tile[kl][n4 + 1] = v.y;
    tile[kl][n4 + 2] = v.z; tile[kl][n4 + 3] = v.w;
  }
  __syncthreads();
  const int nl = tid >> 3, k4 = (tid & 7) * 4;
  u16 h[4], lo[4];
#pragma unroll
  for (int j = 0; j < 4; ++j) f16split(tile[k4 + j][nl], h[j], lo[j]);
  const size_t o = (size_t)(n0 + nl) * K + k0 + k4;
  *(u64*)(Ph + o) = pack4(h[0], h[1], h[2], h[3]);
  *(u64*)(Pl + o) = pack4(lo[0], lo[1], lo[2], lo[3]);
}

// ---------------- x -> h/l fp16 planes (row-major) ---------------------------
__global__ __launch_bounds__(256) void xsplit(
    const float* __restrict__ x, u16* __restrict__ Xh, u16* __restrict__ Xl) {
  const int i = (blockIdx.x * 256 + threadIdx.x) * 4;
  float4 v = *(const float4*)(x + i);
  float e[4] = {v.x, v.y, v.z, v.w};
  u16 h[4], lo[4];
#pragma unroll
  for (int j = 0; j < 4; ++j) f16split(e[j], h[j], lo[j]);
  *(u64*)(Xh + i) = pack4(h[0], h[1], h[2], h[3]);
  *(u64*)(Xl + i) = pack4(lo[0], lo[1], lo[2], lo[3]);
}

// ---------------- fp16-split MFMA GEMM ---------------------------------------
// NPROD=1: C = Ah@Bh (single product). NPROD=3: + Ah@Bl + Al@Bh.
// OUT: 0 = fp32 C; 1 = fp16 h-plane Ch;
//      2 = indexer epilogue (qi-> x2 planes rows bt*4+head, ki-> x2, kr fp32)
//      3 = I epilogue: I[t][s] = sum_j IW[j]*relu(acc_j)
struct GArg {
  const u16 *A0, *A1, *B0, *B1;
  float* C; u16* Ch;
  u16 *Qh, *Ql, *Kh, *Kl; float* KR; const float* IW;
  int lda, ldc, K, nbn;
};

template <int NPROD, int OUT>
__global__ __launch_bounds__(256) void mfma_gemm(GArg g0, GArg g1) {
  GArg g = (blockIdx.z == 0) ? g0 : g1;
  if ((int)blockIdx.x >= g.nbn) return;
  const int NS = (NPROD == 1) ? 1 : 2;
  __shared__ u16 Al[(NPROD == 1 ? 1 : 2) * 5120];
  __shared__ u16 Bl[(NPROD == 1 ? 1 : 2) * 5120];
  const int tid = threadIdx.x;
  const int l = tid & 63, w = tid >> 6;
  const int wr = w >> 1, wc = w & 1;
  const int l15 = l & 15, l4 = l >> 4;
  const int bm = blockIdx.y * 128, bn = blockIdx.x * 128;
  const int ar2 = tid >> 1, akc = (tid & 1) * 16;
  const int brr = tid >> 2, bkc = (tid & 3) * 8;

  f32x4 acc[4][4];
#pragma unroll
  for (int i = 0; i < 4; ++i)
#pragma unroll
    for (int j = 0; j < 4; ++j) acc[i][j] = (f32x4){0.f, 0.f, 0.f, 0.f};

  for (int k0 = 0; k0 < g.K; k0 += 32) {
#pragma unroll
    for (int p = 0; p < NS; ++p) {
      const u16* Ap = (p == 0) ? g.A0 : g.A1;
      const size_t ab = (size_t)(bm + ar2) * g.lda + k0 + akc;
      *(uint4*)&Al[p * 5120 + ar2 * 40 + akc] = *(const uint4*)(Ap + ab);
      *(uint4*)&Al[p * 5120 + ar2 * 40 + akc + 8] = *(const uint4*)(Ap + ab + 8);
      const u16* Bp = (p == 0) ? g.B0 : g.B1;
#pragma unroll
      for (int i = 0; i < 2; ++i) {
        const int row = brr + i * 64;
        *(uint4*)&Bl[p * 5120 + row * 40 + bkc] =
            *(const uint4*)(Bp + (size_t)(bn + row) * g.K + k0 + bkc);
      }
    }
    __syncthreads();
    f16x8 af[NS == 1 ? 1 : 2][4], bf[NS == 1 ? 1 : 2][4];
#pragma unroll
    for (int f = 0; f < 4; ++f) {
      const int arow = wr * 64 + f * 16 + l15;
      const int brow = wc * 64 + f * 16 + l15;
#pragma unroll
      for (int p = 0; p < NS; ++p) {
        af[p][f] = *(const f16x8*)&Al[p * 5120 + arow * 40 + l4 * 8];
        bf[p][f] = *(const f16x8*)&Bl[p * 5120 + brow * 40 + l4 * 8];
      }
    }
#pragma unroll
    for (int fm = 0; fm < 4; ++fm)
#pragma unroll
      for (int fn = 0; fn < 4; ++fn) {
        f32x4 c = acc[fm][fn];
        c = mf16(af[0][fm], bf[0][fn], c);
        if (NPROD == 3) {
          c = mf16(af[0][fm], bf[1][fn], c);
          c = mf16(af[1][fm], bf[0][fn], c);
        }
        acc[fm][fn] = c;
      }
    __syncthreads();
  }
  if (OUT == 3) {
    const float w0 = g.IW[0], w1 = g.IW[1], w2 = g.IW[2], w3 = g.IW[3];
#pragma unroll
    for (int fm = 0; fm < 4; ++fm) {
      const int tt = (bm >> 2) + wr * 16 + fm * 4 + l4;
#pragma unroll
      for (int fn = 0; fn < 4; ++fn) {
        const int col = bn + wc * 64 + fn * 16 + l15;
        const f32x4 a = acc[fm][fn];
        float v = w0 * fmaxf(a[0], 0.f) + w1 * fmaxf(a[1], 0.f)
                + w2 * fmaxf(a[2], 0.f) + w3 * fmaxf(a[3], 0.f);
        g.C[(size_t)tt * g.ldc + col] = v;
      }
    }
    return;
  }
#pragma unroll
  for (int fm = 0; fm < 4; ++fm)
#pragma unroll
    for (int j = 0; j < 4; ++j) {
      const int row = bm + wr * 64 + fm * 16 + l4 * 4 + j;
#pragma unroll
      for (int fn = 0; fn < 4; ++fn) {
        const int col = bn + wc * 64 + fn * 16 + l15;
        const float val = acc[fm][fn][j];
        if (OUT == 0) {
          g.C[(size_t)row * g.ldc + col] = val;
        } else if (OUT == 1) {
          g.Ch[(size_t)row * g.ldc + col] = f16bits(val);
        } else {  // OUT == 2: local cols [qi 256 | ki 64 | kr 32 | pad 32]
          u16 hh, ll;
          f16split(val, hh, ll);
          if (col < 256) {
            const size_t o = ((size_t)row * 4 + (col >> 6)) * 64 + (col & 63);
            g.Qh[o] = hh; g.Ql[o] = ll;
          } else if (col < 320) {
            const size_t o = (size_t)row * 64 + (col - 256);
            g.Kh[o] = hh; g.Kl[o] = ll;
          } else if (col < 352) {
            g.KR[(size_t)row * 32 + (col - 320)] = val;
          }
        }
      }
    }
}

// ------------- TokenSelector top-k over precomputed I[b][t][s] ---------------
__global__ __launch_bounds__(256) void topk2(
    const float* __restrict__ IM, int* __restrict__ idx_sel) {
  const int wave = threadIdx.x >> 6, lane = threadIdx.x & 63;
  const int bt = blockIdx.x * 4 + wave;
  const int b = bt >> 10, t = bt & 1023;
  int* out = idx_sel + (size_t)bt * KTS;
  if (t < LWIN) {
    out[lane] = lane;
    if (lane < 32) out[64 + lane] = 64 + lane;
    return;
  }
  out[lane] = t - 63 + lane;
  const int nf = t - 63;
  const float* Irow = IM + ((size_t)b << 20) + ((size_t)t << 10);
  u64 key[16];
#pragma unroll
  for (int gq = 0; gq < 4; ++gq) {
    const int s0 = gq * 256 + lane * 4;
    float4 v = make_float4(0.f, 0.f, 0.f, 0.f);
    if (s0 < nf) v = *(const float4*)(Irow + s0);
    float e[4] = {v.x, v.y, v.z, v.w};
#pragma unroll
    for (int c = 0; c < 4; ++c) {
      u64 k = 0ull;
      const int s = s0 + c;
      if (s < nf) {
        unsigned ib = __float_as_uint(e[c]);
        if (ib == 0x80000000u) ib = 0u;
        ib = (ib & 0x80000000u) ? ~ib : (ib | 0x80000000u);
        k = ((u64)ib << 32) | (u64)(0xFFFFFFFFu - (unsigned)s);
      }
      key[gq * 4 + c] = k;
    }
  }
  u64 lm = key[0];
#pragma unroll
  for (int j = 1; j < 16; ++j) lm = umax64(lm, key[j]);
  const int topM = nf < 32 ? nf : 32;
  for (int it = 0; it < topM; ++it) {
    u64 m = lm;
#pragma unroll
    for (int off = 32; off > 0; off >>= 1) m = umax64(m, __shfl_xor(m, off));
    if (lane == 0)
      out[64 + it] = (int)(0xFFFFFFFFu - (unsigned)(m & 0xFFFFFFFFull));
    if (lm == m) {
#pragma unroll
      for (int j = 0; j < 16; ++j)
        if (key[j] == m) key[j] = 0ull;
      lm = key[0];
#pragma unroll
      for (int j = 1; j < 16; ++j) lm = umax64(lm, key[j]);
    }
  }
  if (lane < 32 - topM) out[64 + topM + lane] = t + 1 + lane;
}

// ----------------------- sparse attention per (b,t) --------------------------
__global__ __launch_bounds__(256) void attn_kernel(
    const float* __restrict__ qproj, const float* __restrict__ kvproj,
    const float* __restrict__ krc, const int* __restrict__ idx_sel,
    const float* __restrict__ raw_delta, u16* __restrict__ aoh) {
  const int bt = ((blockIdx.x & 7) << 8) | (blockIdx.x >> 3);
  const int b = bt >> 10;
  const int t = bt & 1023;
  const int tid = threadIdx.x;

  __shared__ __align__(16) float qcs[NH * DH];
  __shared__ __align__(16) float qrs[NH * DR];
  __shared__ __align__(16) float krs[KTS * DR];
  __shared__ float scS[NH * 100];
  __shared__ int selS[KTS];
  __shared__ int offS[KTS];
  __shared__ float thetav[16], deltav[16];
  __shared__ float mu[NH * DR];

  const float* qrow = qproj + (size_t)bt * NQP;
  qcs[tid] = qrow[tid];
  qcs[256 + tid] = qrow[256 + tid];
  mu[tid] = softplusf(qrow[512 + tid]);
  if (tid < KTS) {
    int s = idx_sel[(size_t)bt * KTS + tid];
    selS[tid] = s;
    offS[tid] = s * NKV;
  }
  if (tid < 16) {
    thetav[tid] = (float)(1.0 / pow(10000.0, (double)tid / 16.0));
    float r = raw_delta[tid];
    deltav[tid] = -6.2831853071795864769f * (1.f / (1.f + expf(-r)));
  }
  __syncthreads();

  if (tid < 128) {
    int h = tid >> 4, i = tid & 15;
    float ang = (float)t * thetav[i] + deltav[i];
    float c = cosf(ang), s = sinf(ang);
    float m1 = mu[h * DR + i], m2 = mu[h * DR + 16 + i];
    qrs[h * DR + i] = m1 * c - m2 * s;
    qrs[h * DR + 16 + i] = m1 * s + m2 * c;
  }
  const float* krb = krc + (size_t)b * L * 32;
  for (int e = tid; e < KTS * 16; e += 256) {
    int k = e >> 4, i = e & 15;
    int s = selS[k];
    float x1 = krb[(size_t)s * 32 + i];
    float x2 = krb[(size_t)s * 32 + 16 + i];
    float m1 = softplusf(x1), m2 = softplusf(x2);
    float ang = (float)k * thetav[i] + deltav[i];
    float c = cosf(ang), sn = sinf(ang);
    krs[k * DR + i] = m1 * c - m2 * sn;
    krs[k * DR + 16 + i] = m1 * sn + m2 * c;
  }
  __syncthreads();

  const float scale = 0.10206207261596575f;  // (64+32)^-0.5
  const int h = tid >> 5;
  const int l = tid & 31;
  const float2 qv = *(const float2*)&qcs[h * DH + 2 * l];
  const float qr1 = qrs[h * DR + l];
  const float* kvb = kvproj + (size_t)b * L * NKV;
#pragma unroll 8
  for (int k = 0; k < KTS; ++k) {
    const float2 kv = *(const float2*)(kvb + offS[k] + 2 * tid);
    float p = qv.x * kv.x + qv.y * kv.y + qr1 * krs[k * DR + l];
#pragma unroll
    for (int off = 16; off > 0; off >>= 1) p += __shfl_xor(p, off, 32);
    if (l == 0) scS[h * 100 + k] = p * scale;
  }
  __syncthreads();

  {
    float s0 = scS[h * 100 + l], s1 = scS[h * 100 + l + 32],
          s2 = scS[h * 100 + l + 64];
    float mx = fmaxf(fmaxf(s0, s1), s2);
#pragma unroll
    for (int off = 16; off > 0; off >>= 1) mx = fmaxf(mx, __shfl_xor(mx, off, 32));
    float e0 = expf(s0 - mx), e1 = expf(s1 - mx), e2 = expf(s2 - mx);
    float sum = e0 + e1 + e2;
#pragma unroll
    for (int off = 16; off > 0; off >>= 1) sum += __shfl_xor(sum, off, 32);
    float inv = 1.f / sum;
    scS[h * 100 + l] = e0 * inv;
    scS[h * 100 + l + 32] = e1 * inv;
    scS[h * 100 + l + 64] = e2 * inv;
  }
  __syncthreads();

  float2 acc = make_float2(0.f, 0.f);
#pragma unroll 4
  for (int k = 0; k < KTS; ++k) {
    const float2 v = *(const float2*)(kvb + offS[k] + 512 + 2 * tid);
    const float w = scS[h * 100 + k];
    acc.x += w * v.x;
    acc.y += w * v.y;
  }
  const size_t o = (size_t)bt * 512 + 2 * tid;
  *(u32*)(aoh + o) = (u32)f16bits(acc.x) | ((u32)f16bits(acc.y) << 16);
}

// -----------------------------------------------------------------------------
extern "C" void kernel_launch(void* const* d_in, const int* in_sizes, int n_in,
                              void* d_out, int out_size, void* d_ws, size_t ws_size,
                              hipStream_t stream) {
  const float* x      = (const float*)d_in[0];
  const float* W_dkv  = (const float*)d_in[1];
  const float* W_uk   = (const float*)d_in[2];
  const float* W_uv   = (const float*)d_in[3];
  const float* W_dq   = (const float*)d_in[4];
  const float* W_uq   = (const float*)d_in[5];
  const float* W_qr   = (const float*)d_in[6];
  const float* W_kr   = (const float*)d_in[7];
  const float* W_out  = (const float*)d_in[8];
  const float* idx_wq = (const float*)d_in[9];
  const float* idx_wk = (const float*)d_in[10];
  const float* idx_w  = (const float*)d_in[11];
  const float* raw_dl = (const float*)d_in[12];
  float* out = (float*)d_out;

  const int M = 2 * L;  // 2048
  // ---- workspace ----
  u16* BxT_h  = (u16*)d_ws;                       // 1152*1024 x2
  u16* BxT_l  = BxT_h + 1152 * 1024;
  u16* BkvT_h = BxT_l + 1152 * 1024;              // 1024*256 x2
  u16* BkvT_l = BkvT_h + 1024 * 256;
  u16* BqT_h  = BkvT_l + 1024 * 256;              // 768*512 x2
  u16* BqT_l  = BqT_h + 768 * 512;
  u16* WoT_h  = BqT_l + 768 * 512;                // 1024*512 x2
  u16* WoT_l  = WoT_h + 1024 * 512;
  u16* Xh     = WoT_l + 1024 * 512;               // 2048*1024 x2 (dead after G1b)
  u16* Xl     = Xh + (size_t)M * 1024;
  u16* XPh    = Xl + (size_t)M * 1024;            // 2048*768
  u16* AOh    = XPh + (size_t)M * 768;            // 2048*512
  u16* Qih    = AOh + (size_t)M * 512;            // 8192*64 x2 (rows bt*4+h)
  u16* Qil    = Qih + (size_t)M * 4 * 64;
  u16* Kih    = Qil + (size_t)M * 4 * 64;         // 2048*64 x2
  u16* Kil    = Kih + (size_t)M * 64;
  float* krc    = (float*)(Kil + (size_t)M * 64); // 2048*32
  float* kvproj = krc + (size_t)M * 32;           // 2048*1024
  float* qproj  = kvproj + (size_t)M * NKV;       // 2048*768
  int* sel      = (int*)(qproj + (size_t)M * NQP);
  float* IM     = (float*)Xh;                     // 2*1024*1024 f32 (aliases X)

  dim3 blk(256);
  TSrc z = {nullptr, 0, 0};
  GArg Z = {};
  // ---- weight prep ----
  {
    TSrc a = {W_dkv, 0, 256}, bq = {W_dq, 256, 512}, c = {idx_wq, 768, 256},
         d = {idx_wk, 1024, 64}, e = {W_kr, 1088, 32};
    hipLaunchKernelGGL(wsplit, dim3(1152 / 32, 1024 / 32), blk, 0, stream,
                       a, bq, c, d, e, 1024, BxT_h, BxT_l);
  }
  {
    TSrc a = {W_uk, 0, 512}, bq = {W_uv, 512, 512};
    hipLaunchKernelGGL(wsplit, dim3(1024 / 32, 256 / 32), blk, 0, stream,
                       a, bq, z, z, z, 256, BkvT_h, BkvT_l);
  }
  {
    TSrc a = {W_uq, 0, 512}, bq = {W_qr, 512, 256};
    hipLaunchKernelGGL(wsplit, dim3(768 / 32, 512 / 32), blk, 0, stream,
                       a, bq, z, z, z, 512, BqT_h, BqT_l);
  }
  {
    TSrc a = {W_out, 0, 1024};
    hipLaunchKernelGGL(wsplit, dim3(1024 / 32, 512 / 32), blk, 0, stream,
                       a, z, z, z, z, 512, WoT_h, WoT_l);
  }
  hipLaunchKernelGGL(xsplit, dim3(M * 1024 / (256 * 4)), blk, 0, stream,
                     x, Xh, Xl);
  // ---- G1a: cols 0..768 (c_kv|c_q), fp16 single product, h-plane out ----
  {
    GArg g = Z;
    g.A0 = Xh; g.B0 = BxT_h;
    g.Ch = XPh; g.lda = 1024; g.ldc = 768; g.K = 1024; g.nbn = 6;
    hipLaunchKernelGGL((mfma_gemm<1, 1>), dim3(6, M / 128, 1), blk, 0, stream,
                       g, g);
  }
  // ---- G1b: cols 768..1152 (qi|ki|kr), fp16 x2, indexer epilogue ----
  {
    GArg g = Z;
    g.A0 = Xh; g.A1 = Xl;
    g.B0 = BxT_h + 768 * 1024; g.B1 = BxT_l + 768 * 1024;
    g.Qh = Qih; g.Ql = Qil; g.Kh = Kih; g.Kl = Kil; g.KR = krc;
    g.lda = 1024; g.ldc = 0; g.K = 1024; g.nbn = 3;
    hipLaunchKernelGGL((mfma_gemm<3, 2>), dim3(3, M / 128, 1), blk, 0, stream,
                       g, g);
  }
  // ---- I-GEMM: I[b][t][s] = sum_h w_h relu(qi_h(t).ki(s)), per-b via z ----
  {
    GArg g0 = Z, g1 = Z;
    g0.A0 = Qih; g0.A1 = Qil; g0.B0 = Kih; g0.B1 = Kil;
    g0.C = IM; g0.IW = idx_w;
    g0.lda = 64; g0.ldc = 1024; g0.K = 64; g0.nbn = 8;
    g1 = g0;
    g1.A0 = Qih + 4096 * 64; g1.A1 = Qil + 4096 * 64;
    g1.B0 = Kih + 1024 * 64; g1.B1 = Kil + 1024 * 64;
    g1.C = IM + 1024 * 1024;
    hipLaunchKernelGGL((mfma_gemm<3, 3>), dim3(8, 32, 2), blk, 0, stream,
                       g0, g1);
  }
  hipLaunchKernelGGL(topk2, dim3(M / 4), blk, 0, stream, IM, sel);
  // ---- G2 (kvproj, K=256) + G3 (qproj, K=512), fp16 single, fused via z ----
  {
    GArg g2 = Z, g3 = Z;
    g2.A0 = XPh; g2.B0 = BkvT_h;
    g2.C = kvproj; g2.lda = 768; g2.ldc = 1024; g2.K = 256; g2.nbn = 8;
    g3.A0 = XPh + 256; g3.B0 = BqT_h;
    g3.C = qproj; g3.lda = 768; g3.ldc = 768; g3.K = 512; g3.nbn = 6;
    hipLaunchKernelGGL((mfma_gemm<1, 0>), dim3(8, M / 128, 2), blk, 0, stream,
                       g2, g3);
  }
  hipLaunchKernelGGL(attn_kernel, dim3(M), blk, 0, stream,
                     qproj, kvproj, krc, sel, raw_dl, AOh);
  // ---- G5: out = ao @ W_out, fp16 single ----
  {
    GArg g = Z;
    g.A0 = AOh; g.B0 = WoT_h;
    g.C = out; g.lda = 512; g.ldc = 1024; g.K = 512; g.nbn = 8;
    hipLaunchKernelGGL((mfma_gemm<1, 0>), dim3(8, M / 128, 1), blk, 0, stream,
                       g, g);
  }
}